// Round 13
// baseline (799.919 us; speedup 1.0000x reference)
//
#include <hip/hip_runtime.h>

#define T_STEPS 1024
#define B_TOT   512
#define VOCAB   1000
#define EMB     64
#define HID     64
#define GATES   256   // 4*HID

typedef float  f32x4  __attribute__((ext_vector_type(4)));
typedef short  bf16x8 __attribute__((ext_vector_type(8)));   // 8 bf16 = 4 VGPRs

__device__ __forceinline__ float fast_rcp(float x)  { return __builtin_amdgcn_rcpf(x); }
__device__ __forceinline__ float fast_exp2(float x) { return __builtin_amdgcn_exp2f(x); }
__device__ __forceinline__ float sigmoid_f(float x) {
    return fast_rcp(1.0f + fast_exp2(-1.4426950408889634f * x));
}
__device__ __forceinline__ float tanh_f(float x) {
    float e = fast_exp2(2.8853900817779268f * x);
    return 1.0f - 2.0f * fast_rcp(e + 1.0f);
}
__device__ __forceinline__ unsigned short f2bf(float x) {   // RNE f32->bf16
    unsigned u = __float_as_uint(x);
    u = u + 0x7FFFu + ((u >> 16) & 1u);
    return (unsigned short)(u >> 16);
}
__device__ __forceinline__ float bf2f(unsigned short h) {
    return __uint_as_float(((unsigned)h) << 16);
}

// ---------------------------------------------------------------------------
// Kernel 1: zx table. zx_tab[dir][vocab][col], col = gate*64+unit.
// ---------------------------------------------------------------------------
__global__ __launch_bounds__(256, 4)
void zx_table_kernel(const float* __restrict__ emb,
                     const float* __restrict__ Wx_f, const float* __restrict__ b_f,
                     const float* __restrict__ Wx_b, const float* __restrict__ b_b,
                     float* __restrict__ zx_tab)
{
    const int bid = blockIdx.x;            // 0..1999
    const int dir = bid / VOCAB;
    const int v   = bid - dir * VOCAB;
    const int j   = threadIdx.x;           // gate column

    const float* __restrict__ Wx = dir ? Wx_b : Wx_f;
    const float* __restrict__ bv = dir ? b_b  : b_f;

    __shared__ float4 x4[EMB / 4];
    if (j < EMB / 4) x4[j] = ((const float4*)emb)[v * (EMB / 4) + j];
    __syncthreads();

    float a0 = bv[j], a1 = 0.f, a2 = 0.f, a3 = 0.f;
#pragma unroll
    for (int q = 0; q < EMB / 4; ++q) {
        float4 xv = x4[q];
        a0 = fmaf(xv.x, Wx[(4 * q + 0) * GATES + j], a0);
        a1 = fmaf(xv.y, Wx[(4 * q + 1) * GATES + j], a1);
        a2 = fmaf(xv.z, Wx[(4 * q + 2) * GATES + j], a2);
        a3 = fmaf(xv.w, Wx[(4 * q + 3) * GATES + j], a3);
    }
    zx_tab[(dir * VOCAB + v) * GATES + j] = (a0 + a1) + (a2 + a3);
}

// ---------------------------------------------------------------------------
// Kernel 2: Wh -> bf16 hi/lo B-fragments (MFMA B layout: lane l holds
// B[k=8*(l>>4)+j][n=l&15]). Tile beta = dir*32 + g*8 + kt*4 + nt covers
// k in [kt*32,+32), cols [g*64+nt*16,+16). (Verified correct in R11.)
// ---------------------------------------------------------------------------
__global__ __launch_bounds__(64)
void bfrag_kernel(const float* __restrict__ Wh_f, const float* __restrict__ Wh_b,
                  unsigned short* __restrict__ bhi, unsigned short* __restrict__ blo)
{
    const int beta = blockIdx.x;          // 0..63
    const int dir = beta >> 5, g = (beta >> 3) & 3, kt = (beta >> 2) & 1, nt = beta & 3;
    const int l = threadIdx.x;
    const float* __restrict__ Wh = dir ? Wh_b : Wh_f;

    bf16x8 vhi, vlo;
#pragma unroll
    for (int j = 0; j < 8; ++j) {
        int k   = kt * 32 + (l >> 4) * 8 + j;
        int col = g * 64 + nt * 16 + (l & 15);
        float wv = Wh[k * GATES + col];
        unsigned short hi = f2bf(wv);
        unsigned short lo = f2bf(wv - bf2f(hi));
        vhi[j] = (short)hi;
        vlo[j] = (short)lo;
    }
    ((bf16x8*)bhi)[beta * 64 + l] = vhi;
    ((bf16x8*)blo)[beta * 64 + l] = vlo;
}

// ---------------------------------------------------------------------------
// Kernel 3: recurrence via MFMA, split-bf16, ALL-GATES-IN-LANE mapping.
// 512 blocks = (dir, 2-row group) -> 2 blocks/CU (independent co-resident
// work hides each block's serial chain). 4 waves/block; wave w's m-th MFMA
// uses B col-tile 4m+w (gate m, units 16w..16w+16), so after 24 MFMAs lane
// l<16 holds acc[m][r] = z[row r][gate m][unit 16w+(l&15)] for ALL 4 gates
// -> c/h update is lane-local: NO z exchange, NO second barrier.
// h is split to bf16 hi/lo and written to a parity-double-buffered LDS pair
// (read p / write p^1) -> exactly ONE barrier per step.
// ---------------------------------------------------------------------------
__global__ __launch_bounds__(256, 2)
void lstm_mfma_kernel(const int* __restrict__ tokens,
                      const float* __restrict__ zx_tab,
                      const unsigned short* __restrict__ bhi,
                      const unsigned short* __restrict__ blo,
                      float* __restrict__ out)
{
    const int bid  = blockIdx.x;          // 0..511
    const int dir  = bid >> 8;
    const int rp   = bid & 255;
    const int row0 = rp * 2;
    const int tid  = threadIdx.x;
    const int w    = tid >> 6;            // wave id -> unit sub-block
    const int l    = tid & 63;
    const int lc   = l & 15;
    const int lq   = l >> 4;

    const float* __restrict__ zx = zx_tab + dir * (VOCAB * GATES);
    const int cb = w * 16 + lc;           // this lane's unit (within 0..63)

    // Register-resident B fragments: Bh/Bl[kt][m] = tile (gate m, units of w).
    bf16x8 Bh[2][4], Bl[2][4];
#pragma unroll
    for (int kt = 0; kt < 2; ++kt)
#pragma unroll
        for (int m = 0; m < 4; ++m) {
            int beta = dir * 32 + m * 8 + kt * 4 + w;   // producer: g=m, nt=w
            Bh[kt][m] = ((const bf16x8*)bhi)[beta * 64 + l];
            Bl[kt][m] = ((const bf16x8*)blo)[beta * 64 + l];
        }

    // Parity-double-buffered h (bf16 hi/lo). Pitch 72 ushorts = 144 B:
    // 16B-aligned b128 rows, even bank spread. Rows 2-15 stay zero forever.
    __shared__ unsigned short h_hi[2][16][72];
    __shared__ unsigned short h_lo[2][16][72];
    for (int i = tid; i < 2 * 16 * 72; i += 256) {
        ((unsigned short*)h_hi)[i] = 0;
        ((unsigned short*)h_lo)[i] = 0;
    }

    float c0 = 0.f, h0 = 0.f, c1 = 0.f, h1 = 0.f;   // state (lanes l<16)
    int p = 0;

    const int* __restrict__ tr0 = tokens + (row0 + 0) * T_STEPS;
    const int* __restrict__ tr1 = tokens + (row0 + 1) * T_STEPS;
#define POS(t) (dir ? (T_STEPS - 1 - (t)) : (t))

    int t0c = tr0[POS(0)], t1c = tr1[POS(0)];
    int t0n = tr0[POS(1)], t1n = tr1[POS(1)];

    float zx0[4], zx1[4];
#pragma unroll
    for (int m = 0; m < 4; ++m) {
        zx0[m] = zx[t0c * GATES + m * 64 + cb];
        zx1[m] = zx[t1c * GATES + m * 64 + cb];
    }
    __syncthreads();

#pragma unroll 1
    for (int t = 0; t < T_STEPS; ++t) {
        // ---- A fragments (h of step t-1) from parity p ----
        bf16x8 Ah0 = *(const bf16x8*)&h_hi[p][lc][lq * 8];
        bf16x8 Ah1 = *(const bf16x8*)&h_hi[p][lc][32 + lq * 8];
        bf16x8 Al0 = *(const bf16x8*)&h_lo[p][lc][lq * 8];
        bf16x8 Al1 = *(const bf16x8*)&h_lo[p][lc][32 + lq * 8];

        // ---- prefetch: tokens t+2, zx t+1 (hide under MFMA) ----
        int sp2 = POS((t + 2 < T_STEPS) ? (t + 2) : (T_STEPS - 1));
        int t0f = tr0[sp2], t1f = tr1[sp2];
        float zn0[4], zn1[4];
#pragma unroll
        for (int m = 0; m < 4; ++m) {
            zn0[m] = zx[t0n * GATES + m * 64 + cb];
            zn1[m] = zx[t1n * GATES + m * 64 + cb];
        }

        // ---- 24 MFMA: acc[m] = zx + Ah*Bh + Ah*Bl + Al*Bh (gate m) ----
        f32x4 acc[4];
#pragma unroll
        for (int m = 0; m < 4; ++m) {
            f32x4 a; a[0] = zx0[m]; a[1] = zx1[m]; a[2] = 0.f; a[3] = 0.f;
            a = __builtin_amdgcn_mfma_f32_16x16x32_bf16(Ah0, Bh[0][m], a, 0, 0, 0);
            a = __builtin_amdgcn_mfma_f32_16x16x32_bf16(Ah1, Bh[1][m], a, 0, 0, 0);
            a = __builtin_amdgcn_mfma_f32_16x16x32_bf16(Ah0, Bl[0][m], a, 0, 0, 0);
            a = __builtin_amdgcn_mfma_f32_16x16x32_bf16(Ah1, Bl[1][m], a, 0, 0, 0);
            a = __builtin_amdgcn_mfma_f32_16x16x32_bf16(Al0, Bh[0][m], a, 0, 0, 0);
            a = __builtin_amdgcn_mfma_f32_16x16x32_bf16(Al1, Bh[1][m], a, 0, 0, 0);
            acc[m] = a;
        }

        // ---- lane-local update: rows 0,1 in regs 0,1 (valid on l<16) ----
        if (t0c != 0) {                    // block-uniform Keras mask
            float ig = sigmoid_f(acc[0][0]);
            float fg = sigmoid_f(acc[1][0]);
            float gg = tanh_f(acc[2][0]);
            float og = sigmoid_f(acc[3][0]);
            c0 = fmaf(fg, c0, ig * gg);
            h0 = og * tanh_f(c0);
        }
        if (t1c != 0) {
            float ig = sigmoid_f(acc[0][1]);
            float fg = sigmoid_f(acc[1][1]);
            float gg = tanh_f(acc[2][1]);
            float og = sigmoid_f(acc[3][1]);
            c1 = fmaf(fg, c1, ig * gg);
            h1 = og * tanh_f(c1);
        }

        // ---- h writeback (always: parity buffer carries masked state) ----
        if (l < 16) {
            unsigned short hh0 = f2bf(h0), hl0 = f2bf(h0 - bf2f(hh0));
            unsigned short hh1 = f2bf(h1), hl1 = f2bf(h1 - bf2f(hh1));
            h_hi[p ^ 1][0][cb] = hh0;
            h_hi[p ^ 1][1][cb] = hh1;
            h_lo[p ^ 1][0][cb] = hl0;
            h_lo[p ^ 1][1][cb] = hl1;
        }
        __syncthreads();                   // the ONLY barrier per step
        p ^= 1;

        t0c = t0n; t1c = t1n; t0n = t0f; t1n = t1f;
#pragma unroll
        for (int m = 0; m < 4; ++m) { zx0[m] = zn0[m]; zx1[m] = zn1[m]; }
    }

    if (l < 16) {
        out[(row0 + 0) * (2 * HID) + dir * HID + cb] = h0;
        out[(row0 + 1) * (2 * HID) + dir * HID + cb] = h1;
    }
#undef POS
}

extern "C" void kernel_launch(void* const* d_in, const int* in_sizes, int n_in,
                              void* d_out, int out_size, void* d_ws, size_t ws_size,
                              hipStream_t stream) {
    const int*   tokens = (const int*)  d_in[0];
    const float* emb    = (const float*)d_in[1];
    const float* Wx_f   = (const float*)d_in[2];
    const float* Wh_f   = (const float*)d_in[3];
    const float* b_f    = (const float*)d_in[4];
    const float* Wx_b   = (const float*)d_in[5];
    const float* Wh_b   = (const float*)d_in[6];
    const float* b_b    = (const float*)d_in[7];
    float* out = (float*)d_out;

    // ws: zx table (2,048,000 B) | bhi (65,536 B) | blo (65,536 B)
    float*          zx_tab = (float*)d_ws;
    unsigned short* bhi    = (unsigned short*)((char*)d_ws + 2048000);
    unsigned short* blo    = (unsigned short*)((char*)d_ws + 2048000 + 65536);

    hipLaunchKernelGGL(zx_table_kernel, dim3(2 * VOCAB), dim3(GATES), 0, stream,
                       emb, Wx_f, b_f, Wx_b, b_b, zx_tab);
    hipLaunchKernelGGL(bfrag_kernel, dim3(64), dim3(64), 0, stream,
                       Wh_f, Wh_b, bhi, blo);
    hipLaunchKernelGGL(lstm_mfma_kernel, dim3(512), dim3(256), 0, stream,
                       tokens, zx_tab, bhi, blo, out);
}